// Round 4
// baseline (338.581 us; speedup 1.0000x reference)
//
#include <hip/hip_runtime.h>

// (1/sqrt(3)) * log2(e): folds softmax scale AND exp->exp2 into Wq/bq at init.
// Softmax is shift-invariant; scores are O(+-4) -> no max-subtraction needed
// in fp32 (validated rounds 1-3: identical math passed absmax check).
#define QSCALE 0.83294038f

// Interleaved K|V rows: row k of group g = 12 floats [K0..5, V0..5] at
// g*GSTRIDE + k*12. GSTRIDE=196 (16*12+4): group offsets on disjoint bank
// quads (196 mod 32 = 4) -> broadcast reads conflict-free (r3: conflicts=0).
#define GSTRIDE 196
#define WAVE_FLOATS 784

__global__ __launch_bounds__(256, 2) void attn_seg_kernel(
    const float* __restrict__ x,
    const float* __restrict__ Wq, const float* __restrict__ bq,
    const float* __restrict__ Wk, const float* __restrict__ bk,
    const float* __restrict__ Wv, const float* __restrict__ bv,
    const float* __restrict__ Wo, const float* __restrict__ bo,
    float* __restrict__ out, int total)
{
    __shared__ __align__(16) float lds[4 * WAVE_FLOATS];   // 12.25 KB, K/V only
    const int t   = threadIdx.x;
    const int wv_ = t >> 6;        // wave in block
    const int g   = (t >> 4) & 3;  // 16-lane group = one batch elem
    const int s   = t & 15;        // sequence position
    // SEG = [0, 1*5, 2*3, 3, 4*6]
    const int seg = (s == 0) ? 0 : (s < 6) ? 1 : (s < 9) ? 2 : (s == 9) ? 3 : 4;

    float* const kvg = &lds[wv_ * WAVE_FLOATS + g * GSTRIDE];  // group base
    float* const kvw = kvg + s * 12;                           // my row

    // ---- hoist this lane's weights into VGPRs ONCE (seg fixed per lane) ----
    // 126 floats: the entire steady-state loop then has ZERO weight loads.
    float wqr[36], wkr[36], wvr[36], bqr[6], bkr[6], bvr[6];
    {
        const float4* pq = (const float4*)(Wq + seg * 36);   // seg*144B: 16B-aligned
        const float4* pk = (const float4*)(Wk + seg * 36);
        const float4* pv = (const float4*)(Wv + seg * 36);
        #pragma unroll
        for (int i = 0; i < 9; ++i) {
            float4 a = pq[i];
            wqr[i*4+0] = a.x * QSCALE; wqr[i*4+1] = a.y * QSCALE;
            wqr[i*4+2] = a.z * QSCALE; wqr[i*4+3] = a.w * QSCALE;
            float4 b = pk[i];
            wkr[i*4+0] = b.x; wkr[i*4+1] = b.y; wkr[i*4+2] = b.z; wkr[i*4+3] = b.w;
            float4 c = pv[i];
            wvr[i*4+0] = c.x; wvr[i*4+1] = c.y; wvr[i*4+2] = c.z; wvr[i*4+3] = c.w;
        }
        const float2* q2 = (const float2*)(bq + seg * 6);    // 8B-aligned
        const float2* k2 = (const float2*)(bk + seg * 6);
        const float2* v2 = (const float2*)(bv + seg * 6);
        #pragma unroll
        for (int i = 0; i < 3; ++i) {
            float2 a = q2[i]; bqr[i*2] = a.x * QSCALE; bqr[i*2+1] = a.y * QSCALE;
            float2 b = k2[i]; bkr[i*2] = b.x; bkr[i*2+1] = b.y;
            float2 c = v2[i]; bvr[i*2] = c.x; bvr[i*2+1] = c.y;
        }
    }

    const int step = (int)gridDim.x << 8;   // positions per sweep
    int base = (int)blockIdx.x << 8;        // uniform tile base

    // prologue: x for first tile
    float x0=0.f,x1=0.f,x2=0.f,x3=0.f,x4=0.f,x5=0.f;
    if (base + t < total) {
        const float* xp = x + (size_t)(base + t) * 6;
        float2 a = *(const float2*)(xp);
        float2 b = *(const float2*)(xp + 2);
        float2 c = *(const float2*)(xp + 4);
        x0=a.x; x1=a.y; x2=b.x; x3=b.y; x4=c.x; x5=c.y;
    }

    #pragma unroll 1
    for (; base < total; base += step) {
        const int pos = base + t;
        const bool valid = pos < total;

        // ---- prefetch next tile's x (latency hidden under this tile) ----
        float nx0=0.f,nx1=0.f,nx2=0.f,nx3=0.f,nx4=0.f,nx5=0.f;
        {
            const int npos = base + step + t;
            if (npos < total) {
                const float* xp = x + (size_t)npos * 6;
                float2 a = *(const float2*)(xp);
                float2 b = *(const float2*)(xp + 2);
                float2 c = *(const float2*)(xp + 4);
                nx0=a.x; nx1=a.y; nx2=b.x; nx3=b.y; nx4=c.x; nx5=c.y;
            }
        }

        // ---- K,V projections: pure register FMA (no loads) ----
        float kk[6], vvv[6];
        #pragma unroll
        for (int j = 0; j < 6; ++j) {
            kk[j] = bkr[j] + x0*wkr[j*6+0] + x1*wkr[j*6+1] + x2*wkr[j*6+2]
                           + x3*wkr[j*6+3] + x4*wkr[j*6+4] + x5*wkr[j*6+5];
            vvv[j] = bvr[j] + x0*wvr[j*6+0] + x1*wvr[j*6+1] + x2*wvr[j*6+2]
                            + x3*wvr[j*6+3] + x4*wvr[j*6+4] + x5*wvr[j*6+5];
        }

        // ---- publish interleaved K|V row (3x b128, same-wave consumers) ----
        *(float4*)(kvw)     = make_float4(kk[0], kk[1], kk[2], kk[3]);
        *(float4*)(kvw + 4) = make_float4(kk[4], kk[5], vvv[0], vvv[1]);
        *(float4*)(kvw + 8) = make_float4(vvv[2], vvv[3], vvv[4], vvv[5]);

        // ---- Q projection (pre-scaled weights) overlaps the write drain ----
        float q[6];
        #pragma unroll
        for (int j = 0; j < 6; ++j) {
            q[j] = bqr[j] + x0*wqr[j*6+0] + x1*wqr[j*6+1] + x2*wqr[j*6+2]
                          + x3*wqr[j*6+3] + x4*wqr[j*6+4] + x5*wqr[j*6+5];
        }

        // wave-internal visibility: drain LDS writes, pin ordering
        __builtin_amdgcn_wave_barrier();
        asm volatile("s_waitcnt lgkmcnt(0)" ::: "memory");
        __builtin_amdgcn_sched_barrier(0);

        // ---- fused scores -> exp2 -> sum -> PV (broadcast reads) ----
        float s0 = 0.f, s1 = 0.f;
        float c0=0.f,c1=0.f,c2=0.f,c3=0.f,c4=0.f,c5=0.f;
        #pragma unroll
        for (int k = 0; k < 16; ++k) {
            float4 a = *(const float4*)(kvg + k * 12);      // K0..K3
            float4 b = *(const float4*)(kvg + k * 12 + 4);  // K4,K5,V0,V1
            float4 c = *(const float4*)(kvg + k * 12 + 8);  // V2..V5
            float e0 = __builtin_amdgcn_exp2f(q[0]*a.x + q[1]*a.y + q[2]*a.z);
            float e1 = __builtin_amdgcn_exp2f(q[3]*a.w + q[4]*b.x + q[5]*b.y);
            s0 += e0; s1 += e1;
            c0 += e0*b.z; c1 += e0*b.w; c2 += e0*c.x;
            c3 += e1*c.y; c4 += e1*c.z; c5 += e1*c.w;
        }
        const float i0 = __builtin_amdgcn_rcpf(s0);
        const float i1 = __builtin_amdgcn_rcpf(s1);
        c0 *= i0; c1 *= i0; c2 *= i0;
        c3 *= i1; c4 *= i1; c5 *= i1;

        // ---- output projection: Wo,bo wave-uniform -> LICM'd to SGPRs ----
        float o_[6];
        #pragma unroll
        for (int i = 0; i < 6; ++i) {
            o_[i] = bo[i] + c0*Wo[i*6+0] + c1*Wo[i*6+1] + c2*Wo[i*6+2]
                          + c3*Wo[i*6+3] + c4*Wo[i*6+4] + c5*Wo[i*6+5];
        }
        if (valid) {
            float* op = out + (size_t)pos * 6;
            *(float2*)(op)     = make_float2(o_[0], o_[1]);
            *(float2*)(op + 2) = make_float2(o_[2], o_[3]);
            *(float2*)(op + 4) = make_float2(o_[4], o_[5]);
        }

        // next iteration's ds_writes are same-wave, in-order after the reads
        // above; barrier pins compiler ordering only.
        __builtin_amdgcn_wave_barrier();

        x0=nx0; x1=nx1; x2=nx2; x3=nx3; x4=nx4; x5=nx5;
    }
}

extern "C" void kernel_launch(void* const* d_in, const int* in_sizes, int n_in,
                              void* d_out, int out_size, void* d_ws, size_t ws_size,
                              hipStream_t stream) {
    const float* x  = (const float*)d_in[0];
    const float* Wq = (const float*)d_in[1];
    const float* bq = (const float*)d_in[2];
    const float* Wk = (const float*)d_in[3];
    const float* bk = (const float*)d_in[4];
    const float* Wv = (const float*)d_in[5];
    const float* bv = (const float*)d_in[6];
    const float* Wo = (const float*)d_in[7];
    const float* bo = (const float*)d_in[8];
    float* out = (float*)d_out;

    const int total  = in_sizes[0] / 6;            // B*16 positions
    const int ntiles = (total + 255) / 256;

    // Size the persistent grid to exact residency (cached host-side queries;
    // no alloc/sync -> graph-capture safe).
    static int grid_cap = 0;
    if (grid_cap == 0) {
        int bpc = 0;
        if (hipOccupancyMaxActiveBlocksPerMultiprocessor(&bpc, attn_seg_kernel, 256, 0)
                != hipSuccess || bpc <= 0) bpc = 2;
        hipDeviceProp_t prop;
        int ncu = 256;
        if (hipGetDeviceProperties(&prop, 0) == hipSuccess && prop.multiProcessorCount > 0)
            ncu = prop.multiProcessorCount;
        grid_cap = bpc * ncu;
    }
    const int grid = ntiles < grid_cap ? ntiles : grid_cap;
    attn_seg_kernel<<<grid, 256, 0, stream>>>(x, Wq, bq, Wk, bk, Wv, bv, Wo, bo, out, total);
}

// Round 5
// 265.669 us; speedup vs baseline: 1.2744x; 1.2744x over previous
//
#include <hip/hip_runtime.h>

// (1/sqrt(3)) * log2(e): folds softmax scale AND exp->exp2 into q.
// Softmax is shift-invariant; scores are O(+-4) -> no max-subtraction needed
// in fp32 (validated rounds 1-4: identical math passed absmax check).
#define QSCALE 0.83294038f

// Thread-per-batch-element, zero LDS, zero barriers. K,V live in registers
// (192 VGPRs); weights are wave-uniform -> SGPR/s_load operands (free in FMA).
// amdgpu_waves_per_eu(2,2) pins the allocator to a 256-VGPR budget and
// forbids the "spill to raise occupancy" heuristic that wrecked r1/r4.
__global__ __launch_bounds__(256)
__attribute__((amdgpu_waves_per_eu(2, 2)))
void attn_seg_kernel(
    const float* __restrict__ x,
    const float* __restrict__ Wq, const float* __restrict__ bq,
    const float* __restrict__ Wk, const float* __restrict__ bk,
    const float* __restrict__ Wv, const float* __restrict__ bv,
    const float* __restrict__ Wo, const float* __restrict__ bo,
    float* __restrict__ out, int nelems)
{
    const int e = blockIdx.x * 256 + threadIdx.x;
    if (e >= nelems) return;

    const float* __restrict__ xe = x + (size_t)e * 96;   // 16 pos * 6 dim, 384B-aligned
    float* __restrict__ oe = out + (size_t)e * 96;

    float K[16][6], V[16][6];   // statically indexed everywhere -> registers

    // ---- pass 1: K,V for all 16 positions. Fully unrolled: seg is a
    // compile-time constant per s -> weight reads are s_loads with immediate
    // offsets (SGPR operands, free in v_fma). All x loads aligned dwordx4.
    #pragma unroll
    for (int p = 0; p < 8; ++p) {
        float4 A = *(const float4*)(xe + p * 12);
        float4 B = *(const float4*)(xe + p * 12 + 4);
        float4 C = *(const float4*)(xe + p * 12 + 8);
        float xr[2][6] = {{A.x, A.y, A.z, A.w, B.x, B.y},
                          {B.z, B.w, C.x, C.y, C.z, C.w}};
        #pragma unroll
        for (int h = 0; h < 2; ++h) {
            const int s = p * 2 + h;
            // SEG = [0, 1*5, 2*3, 3, 4*6]
            const int sg = (s == 0) ? 0 : (s < 6) ? 1 : (s < 9) ? 2 : (s == 9) ? 3 : 4;
            const float* wk = Wk + sg * 36;
            const float* wv = Wv + sg * 36;
            #pragma unroll
            for (int j = 0; j < 6; ++j) {
                float aK = bk[sg * 6 + j];
                float aV = bv[sg * 6 + j];
                #pragma unroll
                for (int d = 0; d < 6; ++d) {
                    aK += xr[h][d] * wk[j * 6 + d];
                    aV += xr[h][d] * wv[j * 6 + d];
                }
                K[s][j] = aK;
                V[s][j] = aV;
            }
        }
    }

    // Launder the pointer: pass-2 x reloads must NOT be CSE'd against pass-1
    // loads (CSE keeps all 96 floats live -> guaranteed spill; this was r1's
    // hidden 300 MB of scratch traffic). Reload hits L1 (24.5 KB/wave).
    const float* xq = xe;
    asm volatile("" : "+v"(xq));

    // ---- pass 2: per query-pair: Q proj -> fused score/exp2/sum/PV -> out.
    // `#pragma unroll 1`: keeps code ~6KB (I$-safe); p is wave-uniform so seg
    // and all weight addresses stay scalar (SALU + s_load).
    #pragma unroll 1
    for (int p = 0; p < 8; ++p) {
        float4 A = *(const float4*)(xq + p * 12);
        float4 B = *(const float4*)(xq + p * 12 + 4);
        float4 C = *(const float4*)(xq + p * 12 + 8);
        float xr[2][6] = {{A.x, A.y, A.z, A.w, B.x, B.y},
                          {B.z, B.w, C.x, C.y, C.z, C.w}};
        float o2[12];
        #pragma unroll
        for (int h = 0; h < 2; ++h) {
            const int s = p * 2 + h;
            const int sg = (s == 0) ? 0 : (s < 6) ? 1 : (s < 9) ? 2 : (s == 9) ? 3 : 4;
            const float* wq = Wq + sg * 36;

            float q[6];
            #pragma unroll
            for (int j = 0; j < 6; ++j) {
                float a = bq[sg * 6 + j];
                #pragma unroll
                for (int d = 0; d < 6; ++d) a += xr[h][d] * wq[j * 6 + d];
                q[j] = a * QSCALE;
            }

            // 16 independent key-chains: deep ILP at 2 waves/SIMD
            float s0 = 0.f, s1 = 0.f;
            float c0=0.f,c1=0.f,c2=0.f,c3=0.f,c4=0.f,c5=0.f;
            #pragma unroll
            for (int k = 0; k < 16; ++k) {
                float e0 = __builtin_amdgcn_exp2f(q[0]*K[k][0] + q[1]*K[k][1] + q[2]*K[k][2]);
                float e1 = __builtin_amdgcn_exp2f(q[3]*K[k][3] + q[4]*K[k][4] + q[5]*K[k][5]);
                s0 += e0; s1 += e1;
                c0 += e0*V[k][0]; c1 += e0*V[k][1]; c2 += e0*V[k][2];
                c3 += e1*V[k][3]; c4 += e1*V[k][4]; c5 += e1*V[k][5];
            }
            const float i0 = __builtin_amdgcn_rcpf(s0);
            const float i1 = __builtin_amdgcn_rcpf(s1);
            c0 *= i0; c1 *= i0; c2 *= i0;
            c3 *= i1; c4 *= i1; c5 *= i1;

            // out proj: Wo,bo wave-uniform & loop-invariant -> hoisted SGPRs
            #pragma unroll
            for (int i = 0; i < 6; ++i) {
                o2[h*6+i] = bo[i] + c0*Wo[i*6+0] + c1*Wo[i*6+1] + c2*Wo[i*6+2]
                                  + c3*Wo[i*6+3] + c4*Wo[i*6+4] + c5*Wo[i*6+5];
            }
        }
        // 2 rows collected -> 3 aligned dwordx4 stores (48B, fully dense)
        *(float4*)(oe + p * 12)     = make_float4(o2[0], o2[1], o2[2],  o2[3]);
        *(float4*)(oe + p * 12 + 4) = make_float4(o2[4], o2[5], o2[6],  o2[7]);
        *(float4*)(oe + p * 12 + 8) = make_float4(o2[8], o2[9], o2[10], o2[11]);
    }
}

extern "C" void kernel_launch(void* const* d_in, const int* in_sizes, int n_in,
                              void* d_out, int out_size, void* d_ws, size_t ws_size,
                              hipStream_t stream) {
    const float* x  = (const float*)d_in[0];
    const float* Wq = (const float*)d_in[1];
    const float* bq = (const float*)d_in[2];
    const float* Wk = (const float*)d_in[3];
    const float* bk = (const float*)d_in[4];
    const float* Wv = (const float*)d_in[5];
    const float* bv = (const float*)d_in[6];
    const float* Wo = (const float*)d_in[7];
    const float* bo = (const float*)d_in[8];
    float* out = (float*)d_out;

    const int nelems = in_sizes[0] / 96;         // batch elements
    const int grid   = (nelems + 255) / 256;     // one thread per element
    attn_seg_kernel<<<grid, 256, 0, stream>>>(x, Wq, bq, Wk, bk, Wv, bv, Wo, bo, out, nelems);
}